// Round 1
// baseline (1191.612 us; speedup 1.0000x reference)
//
#include <hip/hip_runtime.h>

// ---------------------------------------------------------------------------
// Deformable conv layer: one block per batch image; image + weights staged in
// LDS; offsets are shared across batch (shape (1,2K^2,Ho,Wo)).
// Layout: activations [B][C][H][W] (contiguous per image).
// ---------------------------------------------------------------------------
template<int CIN, int COUT, int K, int H, int W, int HO, int WO, bool WLDS>
__global__ __launch_bounds__(256)
void deform_layer(const float* __restrict__ x, const float* __restrict__ off,
                  const float* __restrict__ w, const float* __restrict__ bias,
                  float* __restrict__ y)
{
    constexpr int K2  = K * K;
    constexpr int IMG = CIN * H * W;
    constexpr int NT  = 256;

    __shared__ float simg[IMG];
    __shared__ float sw[WLDS ? K2 * COUT * CIN : 1];

    const int tid = threadIdx.x;
    const int b   = blockIdx.x;

    // Stage image (coalesced: contiguous CIN*H*W chunk per image)
    const float* xb = x + (size_t)b * IMG;
    for (int i = tid; i < IMG; i += NT) simg[i] = xb[i];

    // Stage weights transposed w[o][c][k] -> sw[k][o][c]
    if (WLDS) {
        for (int i = tid; i < COUT * CIN * K2; i += NT) {
            int k = i % K2;
            int c = (i / K2) % CIN;
            int o = i / (K2 * CIN);
            sw[(k * COUT + o) * CIN + c] = w[i];
        }
    }
    __syncthreads();

    for (int p = tid; p < HO * WO; p += NT) {
        const int ho = p / WO;
        const int wo = p - ho * WO;

        float acc[COUT];
#pragma unroll
        for (int o = 0; o < COUT; ++o) acc[o] = bias[o];

#pragma unroll 1
        for (int k = 0; k < K2; ++k) {
            const int ky = k / K, kx = k - ky * K;
            const float dy = off[(2 * k)     * HO * WO + p];
            const float dx = off[(2 * k + 1) * HO * WO + p];
            const float py = (float)(ho + ky) + dy;
            const float px = (float)(wo + kx) + dx;
            const float y0f = floorf(py), x0f = floorf(px);
            const float wy = py - y0f, wx = px - x0f;
            const int y0 = (int)y0f, x0 = (int)x0f;
            const int y1 = y0 + 1,  x1 = x0 + 1;
            const bool vy0 = ((unsigned)y0 < (unsigned)H);
            const bool vy1 = ((unsigned)y1 < (unsigned)H);
            const bool vx0 = ((unsigned)x0 < (unsigned)W);
            const bool vx1 = ((unsigned)x1 < (unsigned)W);
            const int cy0 = min(max(y0, 0), H - 1) * W;
            const int cy1 = min(max(y1, 0), H - 1) * W;
            const int cx0 = min(max(x0, 0), W - 1);
            const int cx1 = min(max(x1, 0), W - 1);
            const float w00 = (vy0 && vx0) ? (1.f - wy) * (1.f - wx) : 0.f;
            const float w01 = (vy0 && vx1) ? (1.f - wy) * wx         : 0.f;
            const float w10 = (vy1 && vx0) ? wy * (1.f - wx)         : 0.f;
            const float w11 = (vy1 && vx1) ? wy * wx                 : 0.f;
            const int i00 = cy0 + cx0, i01 = cy0 + cx1;
            const int i10 = cy1 + cx0, i11 = cy1 + cx1;

            float samp[CIN];
#pragma unroll
            for (int c = 0; c < CIN; ++c) {
                const float* sc = simg + c * (H * W);
                samp[c] = w00 * sc[i00] + w01 * sc[i01]
                        + w10 * sc[i10] + w11 * sc[i11];
            }

            if (WLDS) {
                const float* wk = sw + k * COUT * CIN;
#pragma unroll
                for (int o = 0; o < COUT; ++o) {
                    float a = acc[o];
#pragma unroll
                    for (int c = 0; c < CIN; ++c)
                        a = fmaf(wk[o * CIN + c], samp[c], a);
                    acc[o] = a;
                }
            } else {
#pragma unroll
                for (int o = 0; o < COUT; ++o) {
                    float a = acc[o];
#pragma unroll
                    for (int c = 0; c < CIN; ++c)
                        a = fmaf(w[(o * CIN + c) * K2 + k], samp[c], a);
                    acc[o] = a;
                }
            }
        }

        float* yb = y + (size_t)b * COUT * HO * WO;
#pragma unroll
        for (int o = 0; o < COUT; ++o)
            yb[o * (HO * WO) + p] = fmaxf(acc[o], 0.f);
    }
}

// ---------------------------------------------------------------------------
// Fused head: perm gather + FC(676->256) + ReLU + FC(256->10).
// 32 blocks x 256 threads; each block handles 8 batch rows.
// ---------------------------------------------------------------------------
__global__ __launch_bounds__(256)
void fc_head(const float* __restrict__ x6, const float* __restrict__ w7,
             const float* __restrict__ b7, const float* __restrict__ w8,
             const float* __restrict__ b8, const int* __restrict__ perm,
             float* __restrict__ out)
{
    constexpr int BPB = 8;     // batch rows per block
    constexpr int F   = 676;   // 4*169
    __shared__ float sx[BPB][F];
    __shared__ float sh[BPB][256];

    const int tid = threadIdx.x;
    const int b0  = blockIdx.x * BPB;

    // Stage inputs with the spatial permutation folded in:
    // feature i = c*169 + p  <-  x6[b][c*169 + perm[p]]
    for (int i = tid; i < BPB * F; i += 256) {
        int bb = i / F, f = i - bb * F;
        int c = f / 169, p = f - c * 169;
        sx[bb][f] = x6[(size_t)(b0 + bb) * F + c * 169 + perm[p]];
    }
    __syncthreads();

    // FC7: thread = output neuron j (0..255); 8 batch rows per thread.
    float acc[BPB];
#pragma unroll
    for (int bb = 0; bb < BPB; ++bb) acc[bb] = b7[tid];
#pragma unroll 4
    for (int i = 0; i < F; ++i) {
        const float wv = w7[i * 256 + tid];   // coalesced across lanes
#pragma unroll
        for (int bb = 0; bb < BPB; ++bb)
            acc[bb] = fmaf(sx[bb][i], wv, acc[bb]);
    }
#pragma unroll
    for (int bb = 0; bb < BPB; ++bb) sh[bb][tid] = fmaxf(acc[bb], 0.f);
    __syncthreads();

    // FC8: 8 rows x 10 logits = 80 outputs per block.
    if (tid < BPB * 10) {
        int bb = tid / 10, t = tid - bb * 10;
        float a = b8[t];
#pragma unroll 8
        for (int j = 0; j < 256; ++j)
            a = fmaf(sh[bb][j], w8[j * 10 + t], a);
        out[(size_t)(b0 + bb) * 10 + t] = a;
    }
}

// ---------------------------------------------------------------------------
extern "C" void kernel_launch(void* const* d_in, const int* in_sizes, int n_in,
                              void* d_out, int out_size, void* d_ws, size_t ws_size,
                              hipStream_t stream)
{
    const float* x    = (const float*)d_in[0];
    const float* off1 = (const float*)d_in[1];
    const float* w1   = (const float*)d_in[2];
    const float* b1   = (const float*)d_in[3];
    const float* off2 = (const float*)d_in[4];
    const float* w2   = (const float*)d_in[5];
    const float* b2   = (const float*)d_in[6];
    const float* off3 = (const float*)d_in[7];
    const float* w3   = (const float*)d_in[8];
    const float* b3   = (const float*)d_in[9];
    const float* off4 = (const float*)d_in[10];
    const float* w4   = (const float*)d_in[11];
    const float* b4   = (const float*)d_in[12];
    const float* off5 = (const float*)d_in[13];
    const float* w5   = (const float*)d_in[14];
    const float* b5   = (const float*)d_in[15];
    const float* off6 = (const float*)d_in[16];
    const float* w6   = (const float*)d_in[17];
    const float* b6   = (const float*)d_in[18];
    const float* w7   = (const float*)d_in[19];
    const float* b7   = (const float*)d_in[20];
    const float* w8   = (const float*)d_in[21];
    const float* b8   = (const float*)d_in[22];
    const int*   perm = (const int*)d_in[23];
    float* out = (float*)d_out;

    // Ping-pong activation buffers in workspace (floats):
    // buf0 at 0 (holds A1/A3/A5, max 3,936,256 fl)
    // buf1 at 3,936,256 (holds A2/A4/A6, max 6,889,472 fl)
    float* ws  = (float*)d_ws;
    float* a1 = ws;                 // 256*16*31*31 = 3,936,256
    float* a2 = ws + 3936256;       // 256*32*29*29 = 6,889,472
    float* a3 = ws;                 // 256*16*25*25 = 2,560,000
    float* a4 = ws + 3936256;       // 256*16*19*19 = 1,478,656
    float* a5 = ws;                 // 256*8*15*15  =   460,800
    float* a6 = ws + 3936256;       // 256*4*13*13  =   173,056

    const dim3 grid(256), blk(256);
    deform_layer< 1, 16, 3, 33, 33, 31, 31, true><<<grid, blk, 0, stream>>>(x,  off1, w1, b1, a1);
    deform_layer<16, 32, 3, 31, 31, 29, 29, true><<<grid, blk, 0, stream>>>(a1, off2, w2, b2, a2);
    deform_layer<32, 16, 5, 29, 29, 25, 25, true><<<grid, blk, 0, stream>>>(a2, off3, w3, b3, a3);
    deform_layer<16, 16, 7, 25, 25, 19, 19, true><<<grid, blk, 0, stream>>>(a3, off4, w4, b4, a4);
    deform_layer<16,  8, 5, 19, 19, 15, 15, true><<<grid, blk, 0, stream>>>(a4, off5, w5, b5, a5);
    deform_layer< 8,  4, 3, 15, 15, 13, 13, true><<<grid, blk, 0, stream>>>(a5, off6, w6, b6, a6);
    fc_head<<<dim3(32), blk, 0, stream>>>(a6, w7, b7, w8, b8, perm, out);
}

// Round 2
// 670.757 us; speedup vs baseline: 1.7765x; 1.7765x over previous
//
#include <hip/hip_runtime.h>

// ---------------------------------------------------------------------------
// One-time weight transpose: w[o][c][k] -> wT[k][o][c]  (c contiguous so the
// compute kernel's uniform reads merge into s_load_dwordx8/16).
// ---------------------------------------------------------------------------
struct WtArgs {
    const float* src[6];
    int co[6], ci[6], k2[6], dstoff[6];
};

__global__ __launch_bounds__(256)
void transpose_weights(WtArgs a, float* __restrict__ dst0)
{
    const int L = blockIdx.x;
    const float* __restrict__ s = a.src[L];
    float* __restrict__ d = dst0 + a.dstoff[L];
    const int co = a.co[L], ci = a.ci[L], k2 = a.k2[L];
    const int n = co * ci * k2;
    for (int i = threadIdx.x; i < n; i += 256) {
        int k = i % k2;
        int c = (i / k2) % ci;
        int o = i / (k2 * ci);
        d[(k * co + o) * ci + c] = s[i];
    }
}

// ---------------------------------------------------------------------------
// Deformable conv layer: one block per batch image; image staged in LDS;
// weights read via wave-uniform scalar loads (WT: transposed [k][o][c] in ws,
// else original [o][c][k] layout straight from d_in).
// ---------------------------------------------------------------------------
template<int CIN, int COUT, int K, int H, int W, int HO, int WO, int NT, bool WT>
__global__ __launch_bounds__(NT)
void deform_layer(const float* __restrict__ x, const float* __restrict__ off,
                  const float* __restrict__ w, const float* __restrict__ bias,
                  float* __restrict__ y)
{
    constexpr int K2  = K * K;
    constexpr int IMG = CIN * H * W;

    __shared__ float simg[IMG];

    const int tid = threadIdx.x;
    const int b   = blockIdx.x;

    // Stage image (coalesced: contiguous CIN*H*W chunk per image)
    const float* xb = x + (size_t)b * IMG;
    for (int i = tid; i < IMG; i += NT) simg[i] = xb[i];
    __syncthreads();

    for (int p = tid; p < HO * WO; p += NT) {
        const int ho = p / WO;
        const int wo = p - ho * WO;

        float acc[COUT];
#pragma unroll
        for (int o = 0; o < COUT; ++o) acc[o] = bias[o];

#pragma unroll 1
        for (int k = 0; k < K2; ++k) {
            const int ky = k / K, kx = k - ky * K;
            const float dy = off[(2 * k)     * HO * WO + p];
            const float dx = off[(2 * k + 1) * HO * WO + p];
            const float py = (float)(ho + ky) + dy;
            const float px = (float)(wo + kx) + dx;
            const float y0f = floorf(py), x0f = floorf(px);
            const float wy = py - y0f, wx = px - x0f;
            const int y0 = (int)y0f, x0 = (int)x0f;
            const int y1 = y0 + 1,  x1 = x0 + 1;
            const bool vy0 = ((unsigned)y0 < (unsigned)H);
            const bool vy1 = ((unsigned)y1 < (unsigned)H);
            const bool vx0 = ((unsigned)x0 < (unsigned)W);
            const bool vx1 = ((unsigned)x1 < (unsigned)W);
            const int cy0 = min(max(y0, 0), H - 1) * W;
            const int cy1 = min(max(y1, 0), H - 1) * W;
            const int cx0 = min(max(x0, 0), W - 1);
            const int cx1 = min(max(x1, 0), W - 1);
            const float w00 = (vy0 && vx0) ? (1.f - wy) * (1.f - wx) : 0.f;
            const float w01 = (vy0 && vx1) ? (1.f - wy) * wx         : 0.f;
            const float w10 = (vy1 && vx0) ? wy * (1.f - wx)         : 0.f;
            const float w11 = (vy1 && vx1) ? wy * wx                 : 0.f;
            const int i00 = cy0 + cx0, i01 = cy0 + cx1;
            const int i10 = cy1 + cx0, i11 = cy1 + cx1;

            float samp[CIN];
#pragma unroll
            for (int c = 0; c < CIN; ++c) {
                const float* sc = simg + c * (H * W);
                samp[c] = w00 * sc[i00] + w01 * sc[i01]
                        + w10 * sc[i10] + w11 * sc[i11];
            }

            if (WT) {
                // wT[k][o][c], c contiguous; uniform address -> scalar loads
                const float* __restrict__ wk = w + k * (COUT * CIN);
#pragma unroll
                for (int o = 0; o < COUT; ++o) {
                    float a = acc[o];
#pragma unroll
                    for (int c = 0; c < CIN; ++c)
                        a = fmaf(wk[o * CIN + c], samp[c], a);
                    acc[o] = a;
                }
            } else {
#pragma unroll
                for (int o = 0; o < COUT; ++o) {
                    float a = acc[o];
#pragma unroll
                    for (int c = 0; c < CIN; ++c)
                        a = fmaf(w[(o * CIN + c) * K2 + k], samp[c], a);
                    acc[o] = a;
                }
            }
        }

        float* yb = y + (size_t)b * COUT * HO * WO;
#pragma unroll
        for (int o = 0; o < COUT; ++o)
            yb[o * (HO * WO) + p] = fmaxf(acc[o], 0.f);
    }
}

// ---------------------------------------------------------------------------
// Fused head: perm gather + FC(676->256) + ReLU + FC(256->10).
// 64 blocks x 256 threads; each block handles 4 batch rows.
// ---------------------------------------------------------------------------
__global__ __launch_bounds__(256)
void fc_head(const float* __restrict__ x6, const float* __restrict__ w7,
             const float* __restrict__ b7, const float* __restrict__ w8,
             const float* __restrict__ b8, const int* __restrict__ perm,
             float* __restrict__ out)
{
    constexpr int BPB = 4;     // batch rows per block
    constexpr int F   = 676;   // 4*169
    __shared__ float sx[BPB][F];
    __shared__ float sh[BPB][256];

    const int tid = threadIdx.x;
    const int b0  = blockIdx.x * BPB;

    // Stage inputs with the spatial permutation folded in.
    for (int i = tid; i < BPB * F; i += 256) {
        int bb = i / F, f = i - bb * F;
        int c = f / 169, p = f - c * 169;
        sx[bb][f] = x6[(size_t)(b0 + bb) * F + c * 169 + perm[p]];
    }
    __syncthreads();

    // FC7: thread = output neuron j (0..255); BPB batch rows per thread.
    float acc[BPB];
#pragma unroll
    for (int bb = 0; bb < BPB; ++bb) acc[bb] = b7[tid];
#pragma unroll 4
    for (int i = 0; i < F; ++i) {
        const float wv = w7[i * 256 + tid];   // coalesced across lanes
#pragma unroll
        for (int bb = 0; bb < BPB; ++bb)
            acc[bb] = fmaf(sx[bb][i], wv, acc[bb]);
    }
#pragma unroll
    for (int bb = 0; bb < BPB; ++bb) sh[bb][tid] = fmaxf(acc[bb], 0.f);
    __syncthreads();

    // FC8: BPB rows x 10 logits per block.
    if (tid < BPB * 10) {
        int bb = tid / 10, t = tid - bb * 10;
        float a = b8[t];
#pragma unroll 8
        for (int j = 0; j < 256; ++j)
            a = fmaf(sh[bb][j], w8[j * 10 + t], a);
        out[(size_t)(b0 + bb) * 10 + t] = a;
    }
}

// ---------------------------------------------------------------------------
extern "C" void kernel_launch(void* const* d_in, const int* in_sizes, int n_in,
                              void* d_out, int out_size, void* d_ws, size_t ws_size,
                              hipStream_t stream)
{
    const float* x    = (const float*)d_in[0];
    const float* off1 = (const float*)d_in[1];
    const float* w1   = (const float*)d_in[2];
    const float* b1   = (const float*)d_in[3];
    const float* off2 = (const float*)d_in[4];
    const float* w2   = (const float*)d_in[5];
    const float* b2   = (const float*)d_in[6];
    const float* off3 = (const float*)d_in[7];
    const float* w3   = (const float*)d_in[8];
    const float* b3   = (const float*)d_in[9];
    const float* off4 = (const float*)d_in[10];
    const float* w4   = (const float*)d_in[11];
    const float* b4   = (const float*)d_in[12];
    const float* off5 = (const float*)d_in[13];
    const float* w5   = (const float*)d_in[14];
    const float* b5   = (const float*)d_in[15];
    const float* off6 = (const float*)d_in[16];
    const float* w6   = (const float*)d_in[17];
    const float* b6   = (const float*)d_in[18];
    const float* w7   = (const float*)d_in[19];
    const float* b7   = (const float*)d_in[20];
    const float* w8   = (const float*)d_in[21];
    const float* b8   = (const float*)d_in[22];
    const int*   perm = (const int*)d_in[23];
    float* out = (float*)d_out;

    // Weight transpose region sizes (floats): per-layer co*ci*k2
    // L1:144 L2:4608 L3:12800 L4:12544 L5:3200 L6:288  -> total 33584
    const int woff[6] = {0, 144, 4752, 17552, 30096, 33296};
    const int WTOT = 33584;
    const int AOFF = 33792;  // activation region start (aligned)

    float* ws = (float*)d_ws;
    const size_t need = (size_t)(AOFF + 3936256 + 6889472) * sizeof(float);
    const bool useWT = (ws_size >= need);

    float* wt   = ws;
    float* buf0 = useWT ? (ws + AOFF) : ws;          // holds a1/a3/a5
    float* buf1 = buf0 + 3936256;                    // holds a2/a4/a6

    float* a1 = buf0;   // 256*16*31*31 = 3,936,256
    float* a2 = buf1;   // 256*32*29*29 = 6,889,472
    float* a3 = buf0;   // 256*16*25*25 = 2,560,000
    float* a4 = buf1;   // 256*16*19*19 = 1,478,656
    float* a5 = buf0;   // 256*8*15*15  =   460,800
    float* a6 = buf1;   // 256*4*13*13  =   173,056

    const dim3 grid(256);
    const dim3 blk(1024);

    if (useWT) {
        WtArgs wa;
        wa.src[0] = w1; wa.src[1] = w2; wa.src[2] = w3;
        wa.src[3] = w4; wa.src[4] = w5; wa.src[5] = w6;
        const int cos[6] = {16, 32, 16, 16, 8, 4};
        const int cis[6] = {1, 16, 32, 16, 16, 8};
        const int k2s[6] = {9, 9, 25, 49, 25, 9};
        for (int i = 0; i < 6; ++i) {
            wa.co[i] = cos[i]; wa.ci[i] = cis[i];
            wa.k2[i] = k2s[i]; wa.dstoff[i] = woff[i];
        }
        transpose_weights<<<dim3(6), dim3(256), 0, stream>>>(wa, wt);

        deform_layer< 1, 16, 3, 33, 33, 31, 31, 1024, true><<<grid, blk, 0, stream>>>(x,  off1, wt + woff[0], b1, a1);
        deform_layer<16, 32, 3, 31, 31, 29, 29, 1024, true><<<grid, blk, 0, stream>>>(a1, off2, wt + woff[1], b2, a2);
        deform_layer<32, 16, 5, 29, 29, 25, 25, 1024, true><<<grid, blk, 0, stream>>>(a2, off3, wt + woff[2], b3, a3);
        deform_layer<16, 16, 7, 25, 25, 19, 19, 1024, true><<<grid, blk, 0, stream>>>(a3, off4, wt + woff[3], b4, a4);
        deform_layer<16,  8, 5, 19, 19, 15, 15, 1024, true><<<grid, blk, 0, stream>>>(a4, off5, wt + woff[4], b5, a5);
        deform_layer< 8,  4, 3, 15, 15, 13, 13, 1024, true><<<grid, blk, 0, stream>>>(a5, off6, wt + woff[5], b6, a6);
    } else {
        deform_layer< 1, 16, 3, 33, 33, 31, 31, 1024, false><<<grid, blk, 0, stream>>>(x,  off1, w1, b1, a1);
        deform_layer<16, 32, 3, 31, 31, 29, 29, 1024, false><<<grid, blk, 0, stream>>>(a1, off2, w2, b2, a2);
        deform_layer<32, 16, 5, 29, 29, 25, 25, 1024, false><<<grid, blk, 0, stream>>>(a2, off3, w3, b3, a3);
        deform_layer<16, 16, 7, 25, 25, 19, 19, 1024, false><<<grid, blk, 0, stream>>>(a3, off4, w4, b4, a4);
        deform_layer<16,  8, 5, 19, 19, 15, 15, 1024, false><<<grid, blk, 0, stream>>>(a4, off5, w5, b5, a5);
        deform_layer< 8,  4, 3, 15, 15, 13, 13, 1024, false><<<grid, blk, 0, stream>>>(a5, off6, w6, b6, a6);
    }

    fc_head<<<dim3(64), dim3(256), 0, stream>>>(a6, w7, b7, w8, b8, perm, out);
}